// Round 1
// 1723.345 us; speedup vs baseline: 1.1899x; 1.1899x over previous
//
#include <hip/hip_runtime.h>
#include <cstdio>

typedef __attribute__((ext_vector_type(8))) short short8_t;
typedef __attribute__((ext_vector_type(8))) unsigned short ushort8_t;
typedef __attribute__((ext_vector_type(4))) unsigned short us4;
typedef __attribute__((ext_vector_type(4))) float f32x4;

__device__ __forceinline__ unsigned short f2bf(float f) {
  unsigned u = __float_as_uint(f);
  u = u + 0x7FFFu + ((u >> 16) & 1u);
  return (unsigned short)(u >> 16);
}
__device__ __forceinline__ float bf2f(unsigned short h) {
  return __uint_as_float((unsigned)h << 16);
}
__device__ __forceinline__ float lrelu(float x) { return x > 0.f ? x : 0.2f * x; }

// ---------------- conversion / transpose ----------------

__global__ void k_f32_to_bf16(const float* __restrict__ src, unsigned short* __restrict__ dst,
                              size_t ns4, size_t nd4) {
  size_t i = (size_t)blockIdx.x * blockDim.x + threadIdx.x;
  if (i >= nd4) return;
  float4 v = make_float4(0.f, 0.f, 0.f, 0.f);
  if (i < ns4) v = ((const float4*)src)[i];
  us4 u = {f2bf(v.x), f2bf(v.y), f2bf(v.z), f2bf(v.w)};
  ((us4*)dst)[i] = u;
}

// all 6 weight transposes in one launch: grid = 6*256, slot = blockIdx>>8
__global__ void k_transpose_w6(const float* __restrict__ W0, const float* __restrict__ W1,
                               const float* __restrict__ W2, const float* __restrict__ W3,
                               const float* __restrict__ W4, const float* __restrict__ W5,
                               unsigned short* __restrict__ WT) {
  int which = blockIdx.x >> 8, k = blockIdx.x & 255, n = threadIdx.x;
  const float* W = which == 0 ? W0 : which == 1 ? W1 : which == 2 ? W2
                 : which == 3 ? W3 : which == 4 ? W4 : W5;
  WT[(size_t)which * 65536 + n * 256 + k] = f2bf(W[k * 256 + n]);
}

// ---------------- CSR build (fused over the 3 index arrays) ----------------

__global__ void k_count3(const int* __restrict__ hg_node, const int* __restrict__ hg_edge,
                         const int* __restrict__ oe_obj, int* __restrict__ cn,
                         int* __restrict__ ce, int* __restrict__ co, int nE2, int nE1) {
  int e = blockIdx.x * blockDim.x + threadIdx.x;
  if (e < nE2) {
    atomicAdd(&cn[hg_node[e]], 1);
    atomicAdd(&ce[hg_edge[e]], 1);
  }
  if (e < nE1) atomicAdd(&co[oe_obj[e]], 1);
}

__global__ void k_fill3(const int* __restrict__ hg_node, const int* __restrict__ hg_edge,
                        const int* __restrict__ oe_obj, const int* __restrict__ NS,
                        const int* __restrict__ ES, const int* __restrict__ OS,
                        int* __restrict__ curn, int* __restrict__ cure, int* __restrict__ curo,
                        int* __restrict__ permn, int* __restrict__ perme,
                        int* __restrict__ permo, int nE2, int nE1) {
  int e = blockIdx.x * blockDim.x + threadIdx.x;
  if (e < nE2) {
    int sn = hg_node[e];
    permn[NS[sn] + atomicAdd(&curn[sn], 1)] = e;
    int se = hg_edge[e];
    perme[ES[se] + atomicAdd(&cure[se], 1)] = e;
  }
  if (e < nE1) {
    int so = oe_obj[e];
    permo[OS[so] + atomicAdd(&curo[so], 1)] = e;
  }
}

// three single-block exclusive scans running concurrently (block b -> job b).
// starts[0..n] (starts[n] = total). block = 1024.
__global__ __launch_bounds__(1024) void k_scan3(const int* __restrict__ c0, int* __restrict__ s0,
                                                int n0, const int* __restrict__ c1,
                                                int* __restrict__ s1, int n1,
                                                const int* __restrict__ c2, int* __restrict__ s2,
                                                int n2) {
  const int* cnt;
  int* starts;
  int n;
  if (blockIdx.x == 0) { cnt = c0; starts = s0; n = n0; }
  else if (blockIdx.x == 1) { cnt = c1; starts = s1; n = n1; }
  else { cnt = c2; starts = s2; n = n2; }
  __shared__ int wsum[16];
  int tid = threadIdx.x, lane = tid & 63, w = tid >> 6;
  int carry = 0;
  for (int base = 0; base < n; base += 4096) {
    int i0 = base + tid * 4;
    int4 c = make_int4(0, 0, 0, 0);
    if (i0 + 3 < n) c = *(const int4*)(cnt + i0);
    else {
      if (i0 < n) c.x = cnt[i0];
      if (i0 + 1 < n) c.y = cnt[i0 + 1];
      if (i0 + 2 < n) c.z = cnt[i0 + 2];
      if (i0 + 3 < n) c.w = cnt[i0 + 3];
    }
    int tsum = c.x + c.y + c.z + c.w;
    int inc = tsum;
    for (int o = 1; o < 64; o <<= 1) {
      int v = __shfl_up(inc, o);
      if (lane >= o) inc += v;
    }
    if (lane == 63) wsum[w] = inc;
    __syncthreads();
    int woff = 0;
    for (int k = 0; k < w; k++) woff += wsum[k];
    int excl = carry + woff + inc - tsum;
    if (i0 < n) starts[i0] = excl;
    if (i0 + 1 < n) starts[i0 + 1] = excl + c.x;
    if (i0 + 2 < n) starts[i0 + 2] = excl + c.x + c.y;
    if (i0 + 3 < n) starts[i0 + 3] = excl + c.x + c.y + c.z;
    int total = 0;
    for (int k = 0; k < 16; k++) total += wsum[k];
    carry += total;
    __syncthreads();
  }
  if (tid == 0) starts[n] = carry;
}

// ---------------- fused GEMM (+bias+lrelu+skip+LN) ------------------------------------
template <int HAS_SKIP>
__global__ __launch_bounds__(256) void k_gemm_ln(const unsigned short* A,
                                                 const unsigned short* __restrict__ Bt,
                                                 const float* __restrict__ bias,
                                                 const float* __restrict__ gamma,
                                                 const float* __restrict__ beta,
                                                 const unsigned short* skip,
                                                 unsigned short* outb, int rows) {
  __shared__ unsigned short As[64][40];
  __shared__ unsigned short Bs[256][40];
  int tid = threadIdx.x;
  int wave = tid >> 6, lane = tid & 63;
  int quad = lane >> 4, l16 = lane & 15;
  size_t row0 = (size_t)blockIdx.x * 64;

  f32x4 acc[16];
#pragma unroll
  for (int i = 0; i < 16; i++) acc[i] = (f32x4){0.f, 0.f, 0.f, 0.f};

  int ar = tid >> 2, ac = (tid & 3) * 8;
  for (int k0 = 0; k0 < 256; k0 += 32) {
    *(ushort8_t*)&As[ar][ac] = *(const ushort8_t*)&A[(row0 + ar) * 256 + k0 + ac];
    const unsigned short* bp = &Bt[(size_t)tid * 256 + k0];
    *(ushort8_t*)&Bs[tid][0] = *(const ushort8_t*)&bp[0];
    *(ushort8_t*)&Bs[tid][8] = *(const ushort8_t*)&bp[8];
    *(ushort8_t*)&Bs[tid][16] = *(const ushort8_t*)&bp[16];
    *(ushort8_t*)&Bs[tid][24] = *(const ushort8_t*)&bp[24];
    __syncthreads();
    short8_t afrag = *(const short8_t*)&As[wave * 16 + l16][quad * 8];
#pragma unroll
    for (int nt = 0; nt < 16; nt++) {
      short8_t bfrag = *(const short8_t*)&Bs[nt * 16 + l16][quad * 8];
      acc[nt] = __builtin_amdgcn_mfma_f32_16x16x32_bf16(afrag, bfrag, acc[nt], 0, 0, 0);
    }
    __syncthreads();
  }

  size_t rbase = row0 + wave * 16 + quad * 4;
#pragma unroll
  for (int nt = 0; nt < 16; nt++) {
    int col = nt * 16 + l16;
    float bv = bias[col];
#pragma unroll
    for (int r = 0; r < 4; r++) {
      float x = lrelu(acc[nt][r] + bv);
      if (HAS_SKIP) {
        if (rbase + r < (size_t)rows) x += bf2f(skip[(rbase + r) * 256 + col]);
      }
      acc[nt][r] = x;
    }
  }
  float s[4] = {0, 0, 0, 0}, q[4] = {0, 0, 0, 0};
#pragma unroll
  for (int nt = 0; nt < 16; nt++)
#pragma unroll
    for (int r = 0; r < 4; r++) {
      float x = acc[nt][r];
      s[r] += x;
      q[r] += x * x;
    }
#pragma unroll
  for (int o = 1; o < 16; o <<= 1)
#pragma unroll
    for (int r = 0; r < 4; r++) {
      s[r] += __shfl_xor(s[r], o);
      q[r] += __shfl_xor(q[r], o);
    }
  float mr[4], rs[4];
#pragma unroll
  for (int r = 0; r < 4; r++) {
    float m = s[r] * (1.f / 256.f);
    float v = q[r] * (1.f / 256.f) - m * m;
    mr[r] = m;
    rs[r] = rsqrtf(v + 1e-5f);
  }
#pragma unroll
  for (int nt = 0; nt < 16; nt++) {
    int col = nt * 16 + l16;
    float g = gamma[col], bb = beta[col];
#pragma unroll
    for (int r = 0; r < 4; r++) {
      if (rbase + r < (size_t)rows) {
        float y = (acc[nt][r] - mr[r]) * rs[r] * g + bb;
        outb[(rbase + r) * 256 + col] = f2bf(y);
      }
    }
  }
}

// ---------------- fused GEMM for HGNN: XW (bf16, in-place) + s1 = XW@a1 ----------
__global__ __launch_bounds__(256) void k_gemm_xw(unsigned short* A,
                                                 const unsigned short* __restrict__ Bt,
                                                 const float* __restrict__ a1,
                                                 float* __restrict__ s1, int rows) {
  __shared__ unsigned short As[64][40];
  __shared__ unsigned short Bs[256][40];
  int tid = threadIdx.x;
  int wave = tid >> 6, lane = tid & 63;
  int quad = lane >> 4, l16 = lane & 15;
  size_t row0 = (size_t)blockIdx.x * 64;

  f32x4 acc[16];
#pragma unroll
  for (int i = 0; i < 16; i++) acc[i] = (f32x4){0.f, 0.f, 0.f, 0.f};

  int ar = tid >> 2, ac = (tid & 3) * 8;
  for (int k0 = 0; k0 < 256; k0 += 32) {
    *(ushort8_t*)&As[ar][ac] = *(const ushort8_t*)&A[(row0 + ar) * 256 + k0 + ac];
    const unsigned short* bp = &Bt[(size_t)tid * 256 + k0];
    *(ushort8_t*)&Bs[tid][0] = *(const ushort8_t*)&bp[0];
    *(ushort8_t*)&Bs[tid][8] = *(const ushort8_t*)&bp[8];
    *(ushort8_t*)&Bs[tid][16] = *(const ushort8_t*)&bp[16];
    *(ushort8_t*)&Bs[tid][24] = *(const ushort8_t*)&bp[24];
    __syncthreads();
    short8_t afrag = *(const short8_t*)&As[wave * 16 + l16][quad * 8];
#pragma unroll
    for (int nt = 0; nt < 16; nt++) {
      short8_t bfrag = *(const short8_t*)&Bs[nt * 16 + l16][quad * 8];
      acc[nt] = __builtin_amdgcn_mfma_f32_16x16x32_bf16(afrag, bfrag, acc[nt], 0, 0, 0);
    }
    __syncthreads();
  }

  size_t rbase = row0 + wave * 16 + quad * 4;
  float s[4] = {0, 0, 0, 0};
#pragma unroll
  for (int nt = 0; nt < 16; nt++) {
    float av = a1[nt * 16 + l16];
#pragma unroll
    for (int r = 0; r < 4; r++) s[r] += acc[nt][r] * av;
  }
#pragma unroll
  for (int o = 1; o < 16; o <<= 1)
#pragma unroll
    for (int r = 0; r < 4; r++) s[r] += __shfl_xor(s[r], o);
#pragma unroll
  for (int nt = 0; nt < 16; nt++) {
    int col = nt * 16 + l16;
#pragma unroll
    for (int r = 0; r < 4; r++)
      if (rbase + r < (size_t)rows) A[(rbase + r) * 256 + col] = f2bf(acc[nt][r]);
  }
  if (l16 == 0) {
#pragma unroll
    for (int r = 0; r < 4; r++)
      if (rbase + r < (size_t)rows) s1[rbase + r] = s[r];
  }
}

// ---------------- CSR gathers ----------------
// Latency fix: segment degree <= 64 essentially always (Poisson 5.3/16/4), so pass 1
// loads perm/index metadata ONCE lane-parallel (one chained load per LANE), then the
// row-accumulate pass broadcasts indices via __shfl (register op) and only issues the
// payload row load, 1-deep prefetched -> loads of consecutive rows overlap.

// per hyperedge r (one wave): ef[r] = mean of XW[node] rows; s2[r] = ef[r]·a2
__global__ __launch_bounds__(256) void k_edge_gather(const unsigned short* __restrict__ XW,
                                                     const int* __restrict__ ES,
                                                     const int* __restrict__ perm,
                                                     const int* __restrict__ hg_node,
                                                     const float* __restrict__ a2,
                                                     float* __restrict__ EF,
                                                     float* __restrict__ s2, int nEdges) {
  int wave = threadIdx.x >> 6, lane = threadIdx.x & 63;
  int r = blockIdx.x * 4 + wave;
  if (r >= nEdges) return;
  int s = ES[r], e = ES[r + 1];
  int cnt = e - s;
  float4 acc = make_float4(0.f, 0.f, 0.f, 0.f);
  if (cnt <= 64) {
    int myn = 0;
    if (lane < cnt) myn = hg_node[perm[s + lane]];
    if (cnt > 0) {
      int n0 = __shfl(myn, 0);
      us4 u = ((const us4*)(XW + (size_t)n0 * 256))[lane];
      for (int jj = 1; jj < cnt; jj++) {
        int n1 = __shfl(myn, jj);
        us4 un = ((const us4*)(XW + (size_t)n1 * 256))[lane];
        acc.x += bf2f(u.x); acc.y += bf2f(u.y);
        acc.z += bf2f(u.z); acc.w += bf2f(u.w);
        u = un;
      }
      acc.x += bf2f(u.x); acc.y += bf2f(u.y);
      acc.z += bf2f(u.z); acc.w += bf2f(u.w);
    }
  } else {
    for (int j = s; j < e; j++) {
      int n = hg_node[perm[j]];
      us4 u = ((const us4*)(XW + (size_t)n * 256))[lane];
      acc.x += bf2f(u.x); acc.y += bf2f(u.y);
      acc.z += bf2f(u.z); acc.w += bf2f(u.w);
    }
  }
  float inv = 1.f / (float)(cnt > 1 ? cnt : 1);
  acc.x *= inv; acc.y *= inv; acc.z *= inv; acc.w *= inv;
  ((float4*)(EF + (size_t)r * 256))[lane] = acc;
  float4 a = ((const float4*)a2)[lane];
  float d = acc.x * a.x + acc.y * a.y + acc.z * a.z + acc.w * a.w;
  for (int o = 32; o; o >>= 1) d += __shfl_xor(d, o);
  if (lane == 0) s2[r] = d;
}

// per node n (one wave): in-wave softmax over incidences + weighted EF gather + lrelu
template <int WRITE_ATTN>
__global__ __launch_bounds__(256) void k_node_gather(const int* __restrict__ NS,
                                                     const int* __restrict__ perm,
                                                     const int* __restrict__ hg_edge,
                                                     const float* __restrict__ s1,
                                                     const float* __restrict__ s2,
                                                     const float* __restrict__ EF,
                                                     unsigned short* outb, float* outf,
                                                     float* attn_out, int nNodes) {
  int wave = threadIdx.x >> 6, lane = threadIdx.x & 63;
  int n = blockIdx.x * 4 + wave;
  if (n >= nNodes) return;
  int s = NS[n], e = NS[n + 1];
  int cnt = e - s;
  float s1n = s1[n];
  float4 acc = make_float4(0.f, 0.f, 0.f, 0.f);
  if (cnt <= 64) {
    int mye0 = 0, myed = 0;
    float myscore = -3.4e38f;
    bool act = lane < cnt;
    if (act) {
      mye0 = perm[s + lane];
      myed = hg_edge[mye0];
      myscore = lrelu(s1n + s2[myed]);
    }
    float mymax = myscore;
    for (int o = 32; o; o >>= 1) mymax = fmaxf(mymax, __shfl_xor(mymax, o));
    float myexp = act ? __expf(myscore - mymax) : 0.f;
    float mysum = myexp;
    for (int o = 32; o; o >>= 1) mysum += __shfl_xor(mysum, o);
    float zinv = 1.f / fmaxf(mysum, 1e-9f);
    float myw = myexp * zinv;
    if (WRITE_ATTN && act) attn_out[mye0] = myw;
    if (cnt > 0) {
      int ed = __shfl(myed, 0);
      float w = __shfl(myw, 0);
      float4 v = ((const float4*)(EF + (size_t)ed * 256))[lane];
      for (int jj = 1; jj < cnt; jj++) {
        int edn = __shfl(myed, jj);
        float wn = __shfl(myw, jj);
        float4 vn = ((const float4*)(EF + (size_t)edn * 256))[lane];
        acc.x += w * v.x; acc.y += w * v.y;
        acc.z += w * v.z; acc.w += w * v.w;
        v = vn; w = wn;
      }
      acc.x += w * v.x; acc.y += w * v.y;
      acc.z += w * v.z; acc.w += w * v.w;
    }
  } else {
    float mymax = -3.4e38f;
    for (int j = s + lane; j < e; j += 64) {
      int ed = hg_edge[perm[j]];
      mymax = fmaxf(mymax, lrelu(s1n + s2[ed]));
    }
    for (int o = 32; o; o >>= 1) mymax = fmaxf(mymax, __shfl_xor(mymax, o));
    float mysum = 0.f;
    for (int j = s + lane; j < e; j += 64) {
      int ed = hg_edge[perm[j]];
      mysum += __expf(lrelu(s1n + s2[ed]) - mymax);
    }
    for (int o = 32; o; o >>= 1) mysum += __shfl_xor(mysum, o);
    float zinv = 1.f / fmaxf(mysum, 1e-9f);
    for (int j = s; j < e; j++) {
      int e0 = perm[j];
      int ed = hg_edge[e0];
      float w = __expf(lrelu(s1n + s2[ed]) - mymax) * zinv;
      if (WRITE_ATTN) {
        if (lane == 0) attn_out[e0] = w;
      }
      float4 v = ((const float4*)(EF + (size_t)ed * 256))[lane];
      acc.x += w * v.x; acc.y += w * v.y;
      acc.z += w * v.z; acc.w += w * v.w;
    }
  }
  acc.x = lrelu(acc.x); acc.y = lrelu(acc.y);
  acc.z = lrelu(acc.z); acc.w = lrelu(acc.w);
  if (outb) {
    us4 u = {f2bf(acc.x), f2bf(acc.y), f2bf(acc.z), f2bf(acc.w)};
    ((us4*)(outb + (size_t)n * 256))[lane] = u;
  } else {
    ((float4*)(outf + (size_t)n * 256))[lane] = acc;
  }
}

// per object o (one wave): msg[o] = sum of ev rows (bf16 in, bf16 out)
__global__ __launch_bounds__(256) void k_obj_gather(const unsigned short* __restrict__ EVB,
                                                    const int* __restrict__ OS,
                                                    const int* __restrict__ perm,
                                                    const int* __restrict__ oe_ev,
                                                    unsigned short* __restrict__ outb,
                                                    int nObj) {
  int wave = threadIdx.x >> 6, lane = threadIdx.x & 63;
  int o = blockIdx.x * 4 + wave;
  if (o >= nObj) return;
  int s = OS[o], e = OS[o + 1];
  int cnt = e - s;
  float4 acc = make_float4(0.f, 0.f, 0.f, 0.f);
  if (cnt <= 64) {
    int myev = 0;
    if (lane < cnt) myev = oe_ev[perm[s + lane]];
    if (cnt > 0) {
      int v0 = __shfl(myev, 0);
      us4 u = ((const us4*)(EVB + (size_t)v0 * 256))[lane];
      for (int jj = 1; jj < cnt; jj++) {
        int v1 = __shfl(myev, jj);
        us4 un = ((const us4*)(EVB + (size_t)v1 * 256))[lane];
        acc.x += bf2f(u.x); acc.y += bf2f(u.y);
        acc.z += bf2f(u.z); acc.w += bf2f(u.w);
        u = un;
      }
      acc.x += bf2f(u.x); acc.y += bf2f(u.y);
      acc.z += bf2f(u.z); acc.w += bf2f(u.w);
    }
  } else {
    for (int j = s; j < e; j++) {
      int ev = oe_ev[perm[j]];
      us4 u = ((const us4*)(EVB + (size_t)ev * 256))[lane];
      acc.x += bf2f(u.x); acc.y += bf2f(u.y);
      acc.z += bf2f(u.z); acc.w += bf2f(u.w);
    }
  }
  us4 u = {f2bf(acc.x), f2bf(acc.y), f2bf(acc.z), f2bf(acc.w)};
  ((us4*)(outb + (size_t)o * 256))[lane] = u;
}

// ---------------- driver ----------------

extern "C" void kernel_launch(void* const* d_in, const int* in_sizes, int n_in,
                              void* d_out, int out_size, void* d_ws, size_t ws_size,
                              hipStream_t stream) {
  (void)n_in; (void)out_size;
  const float* object_X = (const float*)d_in[0];
  const float* event_X = (const float*)d_in[1];
  const float* Wo = (const float*)d_in[2];   const float* bo = (const float*)d_in[3];
  const float* go = (const float*)d_in[4];   const float* bon = (const float*)d_in[5];
  const float* We = (const float*)d_in[6];   const float* be = (const float*)d_in[7];
  const float* ge = (const float*)d_in[8];   const float* ben = (const float*)d_in[9];
  const float* Wu = (const float*)d_in[10];  const float* bu = (const float*)d_in[11];
  const float* Wl = (const float*)d_in[12];  const float* bl = (const float*)d_in[13];
  const float* g1 = (const float*)d_in[14];  const float* b1 = (const float*)d_in[15];
  const float* g2 = (const float*)d_in[16];  const float* b2 = (const float*)d_in[17];
  const float* Wh1 = (const float*)d_in[18]; const float* ah1 = (const float*)d_in[19];
  const float* Wh2 = (const float*)d_in[20]; const float* ah2 = (const float*)d_in[21];
  const int* oe_ev = (const int*)d_in[22];
  const int* oe_obj = (const int*)d_in[23];
  const int* hg_node = (const int*)d_in[24];
  const int* hg_edge = (const int*)d_in[25];

  const int N_OBJ = in_sizes[0] / 256;
  const int N_EV = in_sizes[1] / 256;
  const int E1 = in_sizes[22];
  const int E2 = in_sizes[24];
  const int NN = N_EV + N_OBJ;
  const int MEV = ((N_EV + 63) / 64) * 64;
  const int MOB = ((N_OBJ + 63) / 64) * 64;
  const int MX = ((NN + 63) / 64) * 64;
  const int EMX = E2 > E1 ? E2 : E1;

  char* p = (char*)d_ws;
  auto take = [&](size_t bytes) {
    char* r = p;
    p += (bytes + 255) & ~(size_t)255;
    return r;
  };
  unsigned short* WT = (unsigned short*)take((size_t)6 * 65536 * 2);  // 0.79 MB
  unsigned short* XBF = (unsigned short*)take((size_t)MX * 256 * 2);  // 76.8 MB  X / XW / h
  unsigned short* SB = (unsigned short*)take((size_t)MOB * 256 * 2);  // 51.2 MB staging
  float* EF = (float*)SB;  // alias: SB dead once the obj2 GEMM has consumed it
  float* S1 = (float*)take((size_t)NN * 4);
  float* S2 = (float*)take((size_t)N_EV * 4);
  int* NS = (int*)take((size_t)(NN + 1) * 4);      // node CSR starts
  int* ES = (int*)take((size_t)(N_EV + 1) * 4);    // edge CSR starts
  int* OS = (int*)take((size_t)(N_OBJ + 1) * 4);   // obj CSR starts
  int* CNTn = (int*)take((size_t)NN * 4);          // counts, reused as fill cursors
  int* CNTe = (int*)take((size_t)N_EV * 4);
  int* CNTo = (int*)take((size_t)N_OBJ * 4);
  int* PERMn = (int*)take((size_t)E2 * 4);
  int* PERMe = (int*)take((size_t)E2 * 4);
  int* PERMo = (int*)take((size_t)E1 * 4);
  size_t need = (size_t)(p - (char*)d_ws);
  if (need > ws_size)
    fprintf(stderr, "[kernel_launch] WS OVERFLOW: need=%zu have=%zu\n", need, ws_size);

  float* out = (float*)d_out;
  // obj skip (bf16, 51.2 MB) lives in d_out — dead region until layer-2 outputs
  unsigned short* OBJB = (unsigned short*)d_out;

  // --- weights -> bf16 transposed (one fused launch; slots: We,Wo,Wu,Wl,Wh1,Wh2) ---
  k_transpose_w6<<<6 * 256, 256, 0, stream>>>(We, Wo, Wu, Wl, Wh1, Wh2, WT);

  if (MX > NN)
    hipMemsetAsync(XBF + (size_t)NN * 256, 0, (size_t)(MX - NN) * 512, stream);

  // --- CSR builds (node/E2, edge/E2, obj/E1), fused ---
  size_t cnt_span = (size_t)((char*)PERMn - (char*)CNTn);  // CNTn..CNTo contiguous
  hipMemsetAsync(CNTn, 0, cnt_span, stream);
  k_count3<<<(EMX + 255) / 256, 256, 0, stream>>>(hg_node, hg_edge, oe_obj, CNTn, CNTe, CNTo,
                                                  E2, E1);
  k_scan3<<<3, 1024, 0, stream>>>(CNTn, NS, NN, CNTe, ES, N_EV, CNTo, OS, N_OBJ);
  hipMemsetAsync(CNTn, 0, cnt_span, stream);
  k_fill3<<<(EMX + 255) / 256, 256, 0, stream>>>(hg_node, hg_edge, oe_obj, NS, ES, OS, CNTn,
                                                 CNTe, CNTo, PERMn, PERMe, PERMo, E2, E1);

  // --- ev = LN(lrelu(event_X@We + be)) -> XBF rows [0,N_EV) bf16 ---
  k_f32_to_bf16<<<((size_t)MEV * 64 + 255) / 256, 256, 0, stream>>>(
      event_X, SB, (size_t)N_EV * 64, (size_t)MEV * 64);
  k_gemm_ln<0><<<MEV / 64, 256, 0, stream>>>(SB, WT + 0 * 65536, be, ge, ben, nullptr, XBF,
                                             N_EV);
  // --- obj = LN(lrelu(object_X@Wo + bo)) -> OBJB bf16 (in d_out) ---
  k_f32_to_bf16<<<((size_t)MOB * 64 + 255) / 256, 256, 0, stream>>>(
      object_X, SB, (size_t)N_OBJ * 64, (size_t)MOB * 64);
  k_gemm_ln<0><<<MOB / 64, 256, 0, stream>>>(SB, WT + 1 * 65536, bo, go, bon, nullptr, OBJB,
                                             N_OBJ);
  // --- msg (CSR gather, bf16) -> SB; obj1 = LN(lrelu(msg@Wu+bu)+obj) -> SB ---
  k_obj_gather<<<(N_OBJ + 3) / 4, 256, 0, stream>>>(XBF, OS, PERMo, oe_ev, SB, N_OBJ);
  k_gemm_ln<1><<<MOB / 64, 256, 0, stream>>>(SB, WT + 2 * 65536, bu, g1, b1, OBJB, SB, N_OBJ);
  // --- obj2 = LN(lrelu(obj1@Wl+bl)+obj1) -> XBF rows [N_EV,NN) bf16 ---
  k_gemm_ln<1><<<MOB / 64, 256, 0, stream>>>(SB, WT + 3 * 65536, bl, g2, b2, SB,
                                             XBF + (size_t)N_EV * 256, N_OBJ);

  // --- HGNN layer 1: h -> XBF bf16 (SB now dead; EF aliases it) ---
  k_gemm_xw<<<MX / 64, 256, 0, stream>>>(XBF, WT + 4 * 65536, ah1, S1, NN);
  k_edge_gather<<<(N_EV + 3) / 4, 256, 0, stream>>>(XBF, ES, PERMe, hg_node, ah1 + 256, EF,
                                                    S2, N_EV);
  k_node_gather<0><<<(NN + 3) / 4, 256, 0, stream>>>(NS, PERMn, hg_edge, S1, S2, EF, XBF,
                                                     nullptr, nullptr, NN);
  // --- HGNN layer 2: h f32 + attn -> d_out ---
  k_gemm_xw<<<MX / 64, 256, 0, stream>>>(XBF, WT + 5 * 65536, ah2, S1, NN);
  k_edge_gather<<<(N_EV + 3) / 4, 256, 0, stream>>>(XBF, ES, PERMe, hg_node, ah2 + 256, EF,
                                                    S2, N_EV);
  k_node_gather<1><<<(NN + 3) / 4, 256, 0, stream>>>(NS, PERMn, hg_edge, S1, S2, EF, nullptr,
                                                     out, out + (size_t)NN * 256, NN);
}

// Round 2
// 1533.412 us; speedup vs baseline: 1.3373x; 1.1239x over previous
//
#include <hip/hip_runtime.h>
#include <cstdio>

typedef __attribute__((ext_vector_type(8))) short short8_t;
typedef __attribute__((ext_vector_type(8))) unsigned short ushort8_t;
typedef __attribute__((ext_vector_type(4))) unsigned short us4;
typedef __attribute__((ext_vector_type(4))) float f32x4;

__device__ __forceinline__ unsigned short f2bf(float f) {
  unsigned u = __float_as_uint(f);
  u = u + 0x7FFFu + ((u >> 16) & 1u);
  return (unsigned short)(u >> 16);
}
__device__ __forceinline__ float bf2f(unsigned short h) {
  return __uint_as_float((unsigned)h << 16);
}
__device__ __forceinline__ float lrelu(float x) { return x > 0.f ? x : 0.2f * x; }

// ---------------- weight transpose ----------------

// all 6 weight transposes in one launch: grid = 6*256, slot = blockIdx>>8
__global__ void k_transpose_w6(const float* __restrict__ W0, const float* __restrict__ W1,
                               const float* __restrict__ W2, const float* __restrict__ W3,
                               const float* __restrict__ W4, const float* __restrict__ W5,
                               unsigned short* __restrict__ WT) {
  int which = blockIdx.x >> 8, k = blockIdx.x & 255, n = threadIdx.x;
  const float* W = which == 0 ? W0 : which == 1 ? W1 : which == 2 ? W2
                 : which == 3 ? W3 : which == 4 ? W4 : W5;
  WT[(size_t)which * 65536 + n * 256 + k] = f2bf(W[k * 256 + n]);
}

// ---------------- CSR build (fused over the 3 index arrays) ----------------

__global__ void k_count3(const int* __restrict__ hg_node, const int* __restrict__ hg_edge,
                         const int* __restrict__ oe_obj, int* __restrict__ cn,
                         int* __restrict__ ce, int* __restrict__ co, int nE2, int nE1) {
  int e = blockIdx.x * blockDim.x + threadIdx.x;
  if (e < nE2) {
    atomicAdd(&cn[hg_node[e]], 1);
    atomicAdd(&ce[hg_edge[e]], 1);
  }
  if (e < nE1) atomicAdd(&co[oe_obj[e]], 1);
}

// fill CSR-ordered VALUE arrays directly (kills the perm->index hop in gathers):
//   PE[node pos]  = (e0, hg_edge[e0])  (int2, one 8B scatter)
//   NDe[edge pos] = hg_node[e]
//   EVo[obj pos]  = oe_ev[e]
__global__ void k_fill3(const int* __restrict__ hg_node, const int* __restrict__ hg_edge,
                        const int* __restrict__ oe_ev, const int* __restrict__ oe_obj,
                        const int* __restrict__ NS, const int* __restrict__ ES,
                        const int* __restrict__ OS, int* __restrict__ curn,
                        int* __restrict__ cure, int* __restrict__ curo,
                        int2* __restrict__ PE, int* __restrict__ NDe, int* __restrict__ EVo,
                        int nE2, int nE1) {
  int e = blockIdx.x * blockDim.x + threadIdx.x;
  if (e < nE2) {
    int sn = hg_node[e], se = hg_edge[e];
    int pn = NS[sn] + atomicAdd(&curn[sn], 1);
    PE[pn] = make_int2(e, se);
    int pe = ES[se] + atomicAdd(&cure[se], 1);
    NDe[pe] = sn;
  }
  if (e < nE1) {
    int so = oe_obj[e];
    int po = OS[so] + atomicAdd(&curo[so], 1);
    EVo[po] = oe_ev[e];
  }
}

// three single-block exclusive scans running concurrently (block b -> job b).
// starts[0..n] (starts[n] = total). block = 1024.
__global__ __launch_bounds__(1024) void k_scan3(const int* __restrict__ c0, int* __restrict__ s0,
                                                int n0, const int* __restrict__ c1,
                                                int* __restrict__ s1, int n1,
                                                const int* __restrict__ c2, int* __restrict__ s2,
                                                int n2) {
  const int* cnt;
  int* starts;
  int n;
  if (blockIdx.x == 0) { cnt = c0; starts = s0; n = n0; }
  else if (blockIdx.x == 1) { cnt = c1; starts = s1; n = n1; }
  else { cnt = c2; starts = s2; n = n2; }
  __shared__ int wsum[16];
  int tid = threadIdx.x, lane = tid & 63, w = tid >> 6;
  int carry = 0;
  for (int base = 0; base < n; base += 4096) {
    int i0 = base + tid * 4;
    int4 c = make_int4(0, 0, 0, 0);
    if (i0 + 3 < n) c = *(const int4*)(cnt + i0);
    else {
      if (i0 < n) c.x = cnt[i0];
      if (i0 + 1 < n) c.y = cnt[i0 + 1];
      if (i0 + 2 < n) c.z = cnt[i0 + 2];
      if (i0 + 3 < n) c.w = cnt[i0 + 3];
    }
    int tsum = c.x + c.y + c.z + c.w;
    int inc = tsum;
    for (int o = 1; o < 64; o <<= 1) {
      int v = __shfl_up(inc, o);
      if (lane >= o) inc += v;
    }
    if (lane == 63) wsum[w] = inc;
    __syncthreads();
    int woff = 0;
    for (int k = 0; k < w; k++) woff += wsum[k];
    int excl = carry + woff + inc - tsum;
    if (i0 < n) starts[i0] = excl;
    if (i0 + 1 < n) starts[i0 + 1] = excl + c.x;
    if (i0 + 2 < n) starts[i0 + 2] = excl + c.x + c.y;
    if (i0 + 3 < n) starts[i0 + 3] = excl + c.x + c.y + c.z;
    int total = 0;
    for (int k = 0; k < 16; k++) total += wsum[k];
    carry += total;
    __syncthreads();
  }
  if (tid == 0) starts[n] = carry;
}

// ---------------- fused GEMM (+bias+lrelu+skip+LN) ------------------------------------
// A_F32: A is row-major f32, converted to bf16 during LDS staging (fuses the old
// k_f32_to_bf16 pass). OOB rows (beyond `rows`) staged as zero.
template <int HAS_SKIP, int A_F32>
__global__ __launch_bounds__(256) void k_gemm_ln(const void* __restrict__ Av,
                                                 const unsigned short* __restrict__ Bt,
                                                 const float* __restrict__ bias,
                                                 const float* __restrict__ gamma,
                                                 const float* __restrict__ beta,
                                                 const unsigned short* skip,
                                                 unsigned short* outb, int rows) {
  __shared__ unsigned short As[64][40];
  __shared__ unsigned short Bs[256][40];
  int tid = threadIdx.x;
  int wave = tid >> 6, lane = tid & 63;
  int quad = lane >> 4, l16 = lane & 15;
  size_t row0 = (size_t)blockIdx.x * 64;

  f32x4 acc[16];
#pragma unroll
  for (int i = 0; i < 16; i++) acc[i] = (f32x4){0.f, 0.f, 0.f, 0.f};

  int ar = tid >> 2, ac = (tid & 3) * 8;
  size_t arow = row0 + ar;
  for (int k0 = 0; k0 < 256; k0 += 32) {
    if (A_F32) {
      float4 f0 = make_float4(0.f, 0.f, 0.f, 0.f), f1 = f0;
      if (arow < (size_t)rows) {
        const float4* ap = (const float4*)((const float*)Av + arow * 256 + k0 + ac);
        f0 = ap[0];
        f1 = ap[1];
      }
      us4 u0 = {f2bf(f0.x), f2bf(f0.y), f2bf(f0.z), f2bf(f0.w)};
      us4 u1 = {f2bf(f1.x), f2bf(f1.y), f2bf(f1.z), f2bf(f1.w)};
      *(us4*)&As[ar][ac] = u0;
      *(us4*)&As[ar][ac + 4] = u1;
    } else {
      *(ushort8_t*)&As[ar][ac] =
          *(const ushort8_t*)&((const unsigned short*)Av)[arow * 256 + k0 + ac];
    }
    const unsigned short* bp = &Bt[(size_t)tid * 256 + k0];
    *(ushort8_t*)&Bs[tid][0] = *(const ushort8_t*)&bp[0];
    *(ushort8_t*)&Bs[tid][8] = *(const ushort8_t*)&bp[8];
    *(ushort8_t*)&Bs[tid][16] = *(const ushort8_t*)&bp[16];
    *(ushort8_t*)&Bs[tid][24] = *(const ushort8_t*)&bp[24];
    __syncthreads();
    short8_t afrag = *(const short8_t*)&As[wave * 16 + l16][quad * 8];
#pragma unroll
    for (int nt = 0; nt < 16; nt++) {
      short8_t bfrag = *(const short8_t*)&Bs[nt * 16 + l16][quad * 8];
      acc[nt] = __builtin_amdgcn_mfma_f32_16x16x32_bf16(afrag, bfrag, acc[nt], 0, 0, 0);
    }
    __syncthreads();
  }

  size_t rbase = row0 + wave * 16 + quad * 4;
#pragma unroll
  for (int nt = 0; nt < 16; nt++) {
    int col = nt * 16 + l16;
    float bv = bias[col];
#pragma unroll
    for (int r = 0; r < 4; r++) {
      float x = lrelu(acc[nt][r] + bv);
      if (HAS_SKIP) {
        if (rbase + r < (size_t)rows) x += bf2f(skip[(rbase + r) * 256 + col]);
      }
      acc[nt][r] = x;
    }
  }
  float s[4] = {0, 0, 0, 0}, q[4] = {0, 0, 0, 0};
#pragma unroll
  for (int nt = 0; nt < 16; nt++)
#pragma unroll
    for (int r = 0; r < 4; r++) {
      float x = acc[nt][r];
      s[r] += x;
      q[r] += x * x;
    }
#pragma unroll
  for (int o = 1; o < 16; o <<= 1)
#pragma unroll
    for (int r = 0; r < 4; r++) {
      s[r] += __shfl_xor(s[r], o);
      q[r] += __shfl_xor(q[r], o);
    }
  float mr[4], rs[4];
#pragma unroll
  for (int r = 0; r < 4; r++) {
    float m = s[r] * (1.f / 256.f);
    float v = q[r] * (1.f / 256.f) - m * m;
    mr[r] = m;
    rs[r] = rsqrtf(v + 1e-5f);
  }
#pragma unroll
  for (int nt = 0; nt < 16; nt++) {
    int col = nt * 16 + l16;
    float g = gamma[col], bb = beta[col];
#pragma unroll
    for (int r = 0; r < 4; r++) {
      if (rbase + r < (size_t)rows) {
        float y = (acc[nt][r] - mr[r]) * rs[r] * g + bb;
        outb[(rbase + r) * 256 + col] = f2bf(y);
      }
    }
  }
}

// ---------------- fused GEMM for HGNN: XW (bf16, in-place) + s1 = XW@a1 ----------
__global__ __launch_bounds__(256) void k_gemm_xw(unsigned short* A,
                                                 const unsigned short* __restrict__ Bt,
                                                 const float* __restrict__ a1,
                                                 float* __restrict__ s1, int rows) {
  __shared__ unsigned short As[64][40];
  __shared__ unsigned short Bs[256][40];
  int tid = threadIdx.x;
  int wave = tid >> 6, lane = tid & 63;
  int quad = lane >> 4, l16 = lane & 15;
  size_t row0 = (size_t)blockIdx.x * 64;

  f32x4 acc[16];
#pragma unroll
  for (int i = 0; i < 16; i++) acc[i] = (f32x4){0.f, 0.f, 0.f, 0.f};

  int ar = tid >> 2, ac = (tid & 3) * 8;
  for (int k0 = 0; k0 < 256; k0 += 32) {
    *(ushort8_t*)&As[ar][ac] = *(const ushort8_t*)&A[(row0 + ar) * 256 + k0 + ac];
    const unsigned short* bp = &Bt[(size_t)tid * 256 + k0];
    *(ushort8_t*)&Bs[tid][0] = *(const ushort8_t*)&bp[0];
    *(ushort8_t*)&Bs[tid][8] = *(const ushort8_t*)&bp[8];
    *(ushort8_t*)&Bs[tid][16] = *(const ushort8_t*)&bp[16];
    *(ushort8_t*)&Bs[tid][24] = *(const ushort8_t*)&bp[24];
    __syncthreads();
    short8_t afrag = *(const short8_t*)&As[wave * 16 + l16][quad * 8];
#pragma unroll
    for (int nt = 0; nt < 16; nt++) {
      short8_t bfrag = *(const short8_t*)&Bs[nt * 16 + l16][quad * 8];
      acc[nt] = __builtin_amdgcn_mfma_f32_16x16x32_bf16(afrag, bfrag, acc[nt], 0, 0, 0);
    }
    __syncthreads();
  }

  size_t rbase = row0 + wave * 16 + quad * 4;
  float s[4] = {0, 0, 0, 0};
#pragma unroll
  for (int nt = 0; nt < 16; nt++) {
    float av = a1[nt * 16 + l16];
#pragma unroll
    for (int r = 0; r < 4; r++) s[r] += acc[nt][r] * av;
  }
#pragma unroll
  for (int o = 1; o < 16; o <<= 1)
#pragma unroll
    for (int r = 0; r < 4; r++) s[r] += __shfl_xor(s[r], o);
#pragma unroll
  for (int nt = 0; nt < 16; nt++) {
    int col = nt * 16 + l16;
#pragma unroll
    for (int r = 0; r < 4; r++)
      if (rbase + r < (size_t)rows) A[(rbase + r) * 256 + col] = f2bf(acc[nt][r]);
  }
  if (l16 == 0) {
#pragma unroll
    for (int r = 0; r < 4; r++)
      if (rbase + r < (size_t)rows) s1[rbase + r] = s[r];
  }
}

// ---------------- CSR gathers ----------------
// Pass 1 loads CSR-ordered metadata lane-parallel (single hop, values stored by
// k_fill3). Accumulate pass broadcasts via __shfl and issues row loads in batches
// of 8 -> 8 loads in flight per wave (MLP). Padded terms contribute exactly 0.

// per hyperedge r (one wave): ef[r] = mean of XW[node] rows; s2[r] = ef[r]·a2
__global__ __launch_bounds__(256) void k_edge_gather(const unsigned short* __restrict__ XW,
                                                     const int* __restrict__ ES,
                                                     const int* __restrict__ NDe,
                                                     const float* __restrict__ a2,
                                                     float* __restrict__ EF,
                                                     float* __restrict__ s2, int nEdges) {
  int wave = threadIdx.x >> 6, lane = threadIdx.x & 63;
  int r = blockIdx.x * 4 + wave;
  if (r >= nEdges) return;
  int s = ES[r], e = ES[r + 1];
  int cnt = e - s;
  float4 acc = make_float4(0.f, 0.f, 0.f, 0.f);
  if (cnt <= 64) {
    int myn = 0;
    if (lane < cnt) myn = NDe[s + lane];
    for (int base = 0; base < cnt; base += 8) {
      us4 u[8];
      float f[8];
#pragma unroll
      for (int t = 0; t < 8; t++) {
        int j2 = base + t;  // <= 63 always (cnt <= 64)
        int n1 = __shfl(myn, j2);
        u[t] = ((const us4*)(XW + (size_t)n1 * 256))[lane];
        f[t] = (j2 < cnt) ? 1.f : 0.f;
      }
#pragma unroll
      for (int t = 0; t < 8; t++) {
        acc.x += f[t] * bf2f(u[t].x);
        acc.y += f[t] * bf2f(u[t].y);
        acc.z += f[t] * bf2f(u[t].z);
        acc.w += f[t] * bf2f(u[t].w);
      }
    }
  } else {
    for (int j = s; j < e; j++) {
      int n = NDe[j];
      us4 u = ((const us4*)(XW + (size_t)n * 256))[lane];
      acc.x += bf2f(u.x); acc.y += bf2f(u.y);
      acc.z += bf2f(u.z); acc.w += bf2f(u.w);
    }
  }
  float inv = 1.f / (float)(cnt > 1 ? cnt : 1);
  acc.x *= inv; acc.y *= inv; acc.z *= inv; acc.w *= inv;
  ((float4*)(EF + (size_t)r * 256))[lane] = acc;
  float4 a = ((const float4*)a2)[lane];
  float d = acc.x * a.x + acc.y * a.y + acc.z * a.z + acc.w * a.w;
  for (int o = 32; o; o >>= 1) d += __shfl_xor(d, o);
  if (lane == 0) s2[r] = d;
}

// per node n (one wave): in-wave softmax over incidences + weighted EF gather + lrelu
template <int WRITE_ATTN>
__global__ __launch_bounds__(256) void k_node_gather(const int* __restrict__ NS,
                                                     const int2* __restrict__ PE,
                                                     const float* __restrict__ s1,
                                                     const float* __restrict__ s2,
                                                     const float* __restrict__ EF,
                                                     unsigned short* outb, float* outf,
                                                     float* attn_out, int nNodes) {
  int wave = threadIdx.x >> 6, lane = threadIdx.x & 63;
  int n = blockIdx.x * 4 + wave;
  if (n >= nNodes) return;
  int s = NS[n], e = NS[n + 1];
  int cnt = e - s;
  float s1n = s1[n];
  float4 acc = make_float4(0.f, 0.f, 0.f, 0.f);
  if (cnt <= 64) {
    int mye0 = 0, myed = 0;
    float myscore = -3.4e38f;
    bool act = lane < cnt;
    if (act) {
      int2 pe = PE[s + lane];
      mye0 = pe.x;
      myed = pe.y;
      myscore = lrelu(s1n + s2[myed]);
    }
    float mymax = myscore;
    for (int o = 32; o; o >>= 1) mymax = fmaxf(mymax, __shfl_xor(mymax, o));
    float myexp = act ? __expf(myscore - mymax) : 0.f;
    float mysum = myexp;
    for (int o = 32; o; o >>= 1) mysum += __shfl_xor(mysum, o);
    float zinv = 1.f / fmaxf(mysum, 1e-9f);
    float myw = myexp * zinv;  // == 0 for inactive lanes
    if (WRITE_ATTN && act) attn_out[mye0] = myw;
    for (int base = 0; base < cnt; base += 8) {
      float4 v[8];
      float w[8];
#pragma unroll
      for (int t = 0; t < 8; t++) {
        int j2 = base + t;  // <= 63 always
        int ed = __shfl(myed, j2);
        w[t] = __shfl(myw, j2);
        v[t] = ((const float4*)(EF + (size_t)ed * 256))[lane];
      }
#pragma unroll
      for (int t = 0; t < 8; t++) {
        acc.x += w[t] * v[t].x;
        acc.y += w[t] * v[t].y;
        acc.z += w[t] * v[t].z;
        acc.w += w[t] * v[t].w;
      }
    }
  } else {
    float mymax = -3.4e38f;
    for (int j = s + lane; j < e; j += 64) {
      mymax = fmaxf(mymax, lrelu(s1n + s2[PE[j].y]));
    }
    for (int o = 32; o; o >>= 1) mymax = fmaxf(mymax, __shfl_xor(mymax, o));
    float mysum = 0.f;
    for (int j = s + lane; j < e; j += 64) {
      mysum += __expf(lrelu(s1n + s2[PE[j].y]) - mymax);
    }
    for (int o = 32; o; o >>= 1) mysum += __shfl_xor(mysum, o);
    float zinv = 1.f / fmaxf(mysum, 1e-9f);
    for (int j = s; j < e; j++) {
      int2 pe = PE[j];
      float w = __expf(lrelu(s1n + s2[pe.y]) - mymax) * zinv;
      if (WRITE_ATTN) {
        if (lane == 0) attn_out[pe.x] = w;
      }
      float4 v = ((const float4*)(EF + (size_t)pe.y * 256))[lane];
      acc.x += w * v.x; acc.y += w * v.y;
      acc.z += w * v.z; acc.w += w * v.w;
    }
  }
  acc.x = lrelu(acc.x); acc.y = lrelu(acc.y);
  acc.z = lrelu(acc.z); acc.w = lrelu(acc.w);
  if (outb) {
    us4 u = {f2bf(acc.x), f2bf(acc.y), f2bf(acc.z), f2bf(acc.w)};
    ((us4*)(outb + (size_t)n * 256))[lane] = u;
  } else {
    ((float4*)(outf + (size_t)n * 256))[lane] = acc;
  }
}

// per object o (one wave): msg[o] = sum of ev rows (bf16 in, bf16 out)
__global__ __launch_bounds__(256) void k_obj_gather(const unsigned short* __restrict__ EVB,
                                                    const int* __restrict__ OS,
                                                    const int* __restrict__ EVo,
                                                    unsigned short* __restrict__ outb,
                                                    int nObj) {
  int wave = threadIdx.x >> 6, lane = threadIdx.x & 63;
  int o = blockIdx.x * 4 + wave;
  if (o >= nObj) return;
  int s = OS[o], e = OS[o + 1];
  int cnt = e - s;
  float4 acc = make_float4(0.f, 0.f, 0.f, 0.f);
  if (cnt <= 64) {
    int myev = 0;
    if (lane < cnt) myev = EVo[s + lane];
    for (int base = 0; base < cnt; base += 8) {
      us4 u[8];
      float f[8];
#pragma unroll
      for (int t = 0; t < 8; t++) {
        int j2 = base + t;  // <= 63 always
        int v1 = __shfl(myev, j2);
        u[t] = ((const us4*)(EVB + (size_t)v1 * 256))[lane];
        f[t] = (j2 < cnt) ? 1.f : 0.f;
      }
#pragma unroll
      for (int t = 0; t < 8; t++) {
        acc.x += f[t] * bf2f(u[t].x);
        acc.y += f[t] * bf2f(u[t].y);
        acc.z += f[t] * bf2f(u[t].z);
        acc.w += f[t] * bf2f(u[t].w);
      }
    }
  } else {
    for (int j = s; j < e; j++) {
      int ev = EVo[j];
      us4 u = ((const us4*)(EVB + (size_t)ev * 256))[lane];
      acc.x += bf2f(u.x); acc.y += bf2f(u.y);
      acc.z += bf2f(u.z); acc.w += bf2f(u.w);
    }
  }
  us4 u = {f2bf(acc.x), f2bf(acc.y), f2bf(acc.z), f2bf(acc.w)};
  ((us4*)(outb + (size_t)o * 256))[lane] = u;
}

// ---------------- driver ----------------

extern "C" void kernel_launch(void* const* d_in, const int* in_sizes, int n_in,
                              void* d_out, int out_size, void* d_ws, size_t ws_size,
                              hipStream_t stream) {
  (void)n_in; (void)out_size;
  const float* object_X = (const float*)d_in[0];
  const float* event_X = (const float*)d_in[1];
  const float* Wo = (const float*)d_in[2];   const float* bo = (const float*)d_in[3];
  const float* go = (const float*)d_in[4];   const float* bon = (const float*)d_in[5];
  const float* We = (const float*)d_in[6];   const float* be = (const float*)d_in[7];
  const float* ge = (const float*)d_in[8];   const float* ben = (const float*)d_in[9];
  const float* Wu = (const float*)d_in[10];  const float* bu = (const float*)d_in[11];
  const float* Wl = (const float*)d_in[12];  const float* bl = (const float*)d_in[13];
  const float* g1 = (const float*)d_in[14];  const float* b1 = (const float*)d_in[15];
  const float* g2 = (const float*)d_in[16];  const float* b2 = (const float*)d_in[17];
  const float* Wh1 = (const float*)d_in[18]; const float* ah1 = (const float*)d_in[19];
  const float* Wh2 = (const float*)d_in[20]; const float* ah2 = (const float*)d_in[21];
  const int* oe_ev = (const int*)d_in[22];
  const int* oe_obj = (const int*)d_in[23];
  const int* hg_node = (const int*)d_in[24];
  const int* hg_edge = (const int*)d_in[25];

  const int N_OBJ = in_sizes[0] / 256;
  const int N_EV = in_sizes[1] / 256;
  const int E1 = in_sizes[22];
  const int E2 = in_sizes[24];
  const int NN = N_EV + N_OBJ;
  const int MEV = ((N_EV + 63) / 64) * 64;
  const int MOB = ((N_OBJ + 63) / 64) * 64;
  const int MX = ((NN + 63) / 64) * 64;
  const int EMX = E2 > E1 ? E2 : E1;

  char* p = (char*)d_ws;
  auto take = [&](size_t bytes) {
    char* r = p;
    p += (bytes + 255) & ~(size_t)255;
    return r;
  };
  unsigned short* WT = (unsigned short*)take((size_t)6 * 65536 * 2);  // 0.79 MB
  unsigned short* XBF = (unsigned short*)take((size_t)MX * 256 * 2);  // 76.8 MB  X / XW / h
  unsigned short* SB = (unsigned short*)take((size_t)MOB * 256 * 2);  // 51.2 MB staging
  float* EF = (float*)SB;  // alias: SB dead once the obj2 GEMM has consumed it
  float* S1 = (float*)take((size_t)NN * 4);
  float* S2 = (float*)take((size_t)N_EV * 4);
  int* NS = (int*)take((size_t)(NN + 1) * 4);      // node CSR starts
  int* ES = (int*)take((size_t)(N_EV + 1) * 4);    // edge CSR starts
  int* OS = (int*)take((size_t)(N_OBJ + 1) * 4);   // obj CSR starts
  int* CNTn = (int*)take((size_t)NN * 4);          // counts, reused as fill cursors
  int* CNTe = (int*)take((size_t)N_EV * 4);
  int* CNTo = (int*)take((size_t)N_OBJ * 4);
  int2* PEn = (int2*)take((size_t)E2 * 8);         // (e0, hg_edge[e0]) in node-CSR order
  int* NDe = (int*)take((size_t)E2 * 4);           // hg_node values in edge-CSR order
  int* EVo = (int*)take((size_t)E1 * 4);           // oe_ev values in obj-CSR order
  size_t need = (size_t)(p - (char*)d_ws);
  if (need > ws_size)
    fprintf(stderr, "[kernel_launch] WS OVERFLOW: need=%zu have=%zu\n", need, ws_size);

  float* out = (float*)d_out;
  // obj skip (bf16, 51.2 MB) lives in d_out — dead region until layer-2 outputs
  unsigned short* OBJB = (unsigned short*)d_out;

  // --- weights -> bf16 transposed (one fused launch; slots: We,Wo,Wu,Wl,Wh1,Wh2) ---
  k_transpose_w6<<<6 * 256, 256, 0, stream>>>(We, Wo, Wu, Wl, Wh1, Wh2, WT);

  if (MX > NN)
    hipMemsetAsync(XBF + (size_t)NN * 256, 0, (size_t)(MX - NN) * 512, stream);

  // --- CSR builds (node/E2, edge/E2, obj/E1), fused ---
  size_t cnt_span = (size_t)((char*)PEn - (char*)CNTn);  // CNTn..CNTo contiguous
  hipMemsetAsync(CNTn, 0, cnt_span, stream);
  k_count3<<<(EMX + 255) / 256, 256, 0, stream>>>(hg_node, hg_edge, oe_obj, CNTn, CNTe, CNTo,
                                                  E2, E1);
  k_scan3<<<3, 1024, 0, stream>>>(CNTn, NS, NN, CNTe, ES, N_EV, CNTo, OS, N_OBJ);
  hipMemsetAsync(CNTn, 0, cnt_span, stream);
  k_fill3<<<(EMX + 255) / 256, 256, 0, stream>>>(hg_node, hg_edge, oe_ev, oe_obj, NS, ES, OS,
                                                 CNTn, CNTe, CNTo, PEn, NDe, EVo, E2, E1);

  // --- ev = LN(lrelu(event_X@We + be)) -> XBF rows [0,N_EV) bf16 (f32 A fused) ---
  k_gemm_ln<0, 1><<<MEV / 64, 256, 0, stream>>>(event_X, WT + 0 * 65536, be, ge, ben, nullptr,
                                                XBF, N_EV);
  // --- obj = LN(lrelu(object_X@Wo + bo)) -> OBJB bf16 (in d_out) ---
  k_gemm_ln<0, 1><<<MOB / 64, 256, 0, stream>>>(object_X, WT + 1 * 65536, bo, go, bon, nullptr,
                                                OBJB, N_OBJ);
  // --- msg (CSR gather, bf16) -> SB; obj1 = LN(lrelu(msg@Wu+bu)+obj) -> SB ---
  k_obj_gather<<<(N_OBJ + 3) / 4, 256, 0, stream>>>(XBF, OS, EVo, SB, N_OBJ);
  k_gemm_ln<1, 0><<<MOB / 64, 256, 0, stream>>>(SB, WT + 2 * 65536, bu, g1, b1, OBJB, SB,
                                                N_OBJ);
  // --- obj2 = LN(lrelu(obj1@Wl+bl)+obj1) -> XBF rows [N_EV,NN) bf16 ---
  k_gemm_ln<1, 0><<<MOB / 64, 256, 0, stream>>>(SB, WT + 3 * 65536, bl, g2, b2, SB,
                                                XBF + (size_t)N_EV * 256, N_OBJ);

  // --- HGNN layer 1: h -> XBF bf16 (SB now dead; EF aliases it) ---
  k_gemm_xw<<<MX / 64, 256, 0, stream>>>(XBF, WT + 4 * 65536, ah1, S1, NN);
  k_edge_gather<<<(N_EV + 3) / 4, 256, 0, stream>>>(XBF, ES, NDe, ah1 + 256, EF, S2, N_EV);
  k_node_gather<0><<<(NN + 3) / 4, 256, 0, stream>>>(NS, PEn, S1, S2, EF, XBF, nullptr,
                                                     nullptr, NN);
  // --- HGNN layer 2: h f32 + attn -> d_out ---
  k_gemm_xw<<<MX / 64, 256, 0, stream>>>(XBF, WT + 5 * 65536, ah2, S1, NN);
  k_edge_gather<<<(N_EV + 3) / 4, 256, 0, stream>>>(XBF, ES, NDe, ah2 + 256, EF, S2, N_EV);
  k_node_gather<1><<<(NN + 3) / 4, 256, 0, stream>>>(NS, PEn, S1, S2, EF, nullptr, out,
                                                     out + (size_t)NN * 256, NN);
}

// Round 3
// 1433.372 us; speedup vs baseline: 1.4306x; 1.0698x over previous
//
#include <hip/hip_runtime.h>
#include <cstdio>

typedef __attribute__((ext_vector_type(8))) short short8_t;
typedef __attribute__((ext_vector_type(8))) unsigned short ushort8_t;
typedef __attribute__((ext_vector_type(4))) unsigned short us4;
typedef __attribute__((ext_vector_type(4))) float f32x4;

__device__ __forceinline__ unsigned short f2bf(float f) {
  unsigned u = __float_as_uint(f);
  u = u + 0x7FFFu + ((u >> 16) & 1u);
  return (unsigned short)(u >> 16);
}
__device__ __forceinline__ float bf2f(unsigned short h) {
  return __uint_as_float((unsigned)h << 16);
}
__device__ __forceinline__ float lrelu(float x) { return x > 0.f ? x : 0.2f * x; }

// ---------------- weight transpose ----------------

// all 6 weight transposes in one launch: grid = 6*256, slot = blockIdx>>8
__global__ void k_transpose_w6(const float* __restrict__ W0, const float* __restrict__ W1,
                               const float* __restrict__ W2, const float* __restrict__ W3,
                               const float* __restrict__ W4, const float* __restrict__ W5,
                               unsigned short* __restrict__ WT) {
  int which = blockIdx.x >> 8, k = blockIdx.x & 255, n = threadIdx.x;
  const float* W = which == 0 ? W0 : which == 1 ? W1 : which == 2 ? W2
                 : which == 3 ? W3 : which == 4 ? W4 : W5;
  WT[(size_t)which * 65536 + n * 256 + k] = f2bf(W[k * 256 + n]);
}

// ---------------- CSR build (fused over the 3 index arrays) ----------------

__global__ void k_count3(const int* __restrict__ hg_node, const int* __restrict__ hg_edge,
                         const int* __restrict__ oe_obj, int* __restrict__ cn,
                         int* __restrict__ ce, int* __restrict__ co, int nE2, int nE1) {
  int e = blockIdx.x * blockDim.x + threadIdx.x;
  if (e < nE2) {
    atomicAdd(&cn[hg_node[e]], 1);
    atomicAdd(&ce[hg_edge[e]], 1);
  }
  if (e < nE1) atomicAdd(&co[oe_obj[e]], 1);
}

// fill CSR-ordered VALUE arrays directly (kills the perm->index hop in gathers):
//   PE[node pos]  = (e0, hg_edge[e0])  (int2, one 8B scatter)
//   NDe[edge pos] = hg_node[e]
//   EVo[obj pos]  = oe_ev[e]
__global__ void k_fill3(const int* __restrict__ hg_node, const int* __restrict__ hg_edge,
                        const int* __restrict__ oe_ev, const int* __restrict__ oe_obj,
                        const int* __restrict__ NS, const int* __restrict__ ES,
                        const int* __restrict__ OS, int* __restrict__ curn,
                        int* __restrict__ cure, int* __restrict__ curo,
                        int2* __restrict__ PE, int* __restrict__ NDe, int* __restrict__ EVo,
                        int nE2, int nE1) {
  int e = blockIdx.x * blockDim.x + threadIdx.x;
  if (e < nE2) {
    int sn = hg_node[e], se = hg_edge[e];
    int pn = NS[sn] + atomicAdd(&curn[sn], 1);
    PE[pn] = make_int2(e, se);
    int pe = ES[se] + atomicAdd(&cure[se], 1);
    NDe[pe] = sn;
  }
  if (e < nE1) {
    int so = oe_obj[e];
    int po = OS[so] + atomicAdd(&curo[so], 1);
    EVo[po] = oe_ev[e];
  }
}

// three single-block exclusive scans running concurrently (block b -> job b).
// starts[0..n] (starts[n] = total). block = 1024.
__global__ __launch_bounds__(1024) void k_scan3(const int* __restrict__ c0, int* __restrict__ s0,
                                                int n0, const int* __restrict__ c1,
                                                int* __restrict__ s1, int n1,
                                                const int* __restrict__ c2, int* __restrict__ s2,
                                                int n2) {
  const int* cnt;
  int* starts;
  int n;
  if (blockIdx.x == 0) { cnt = c0; starts = s0; n = n0; }
  else if (blockIdx.x == 1) { cnt = c1; starts = s1; n = n1; }
  else { cnt = c2; starts = s2; n = n2; }
  __shared__ int wsum[16];
  int tid = threadIdx.x, lane = tid & 63, w = tid >> 6;
  int carry = 0;
  for (int base = 0; base < n; base += 4096) {
    int i0 = base + tid * 4;
    int4 c = make_int4(0, 0, 0, 0);
    if (i0 + 3 < n) c = *(const int4*)(cnt + i0);
    else {
      if (i0 < n) c.x = cnt[i0];
      if (i0 + 1 < n) c.y = cnt[i0 + 1];
      if (i0 + 2 < n) c.z = cnt[i0 + 2];
      if (i0 + 3 < n) c.w = cnt[i0 + 3];
    }
    int tsum = c.x + c.y + c.z + c.w;
    int inc = tsum;
    for (int o = 1; o < 64; o <<= 1) {
      int v = __shfl_up(inc, o);
      if (lane >= o) inc += v;
    }
    if (lane == 63) wsum[w] = inc;
    __syncthreads();
    int woff = 0;
    for (int k = 0; k < w; k++) woff += wsum[k];
    int excl = carry + woff + inc - tsum;
    if (i0 < n) starts[i0] = excl;
    if (i0 + 1 < n) starts[i0 + 1] = excl + c.x;
    if (i0 + 2 < n) starts[i0 + 2] = excl + c.x + c.y;
    if (i0 + 3 < n) starts[i0 + 3] = excl + c.x + c.y + c.z;
    int total = 0;
    for (int k = 0; k < 16; k++) total += wsum[k];
    carry += total;
    __syncthreads();
  }
  if (tid == 0) starts[n] = carry;
}

// ---------------- fused GEMM (+bias+lrelu+skip+LN) ------------------------------------
// A_F32: A is row-major f32, converted to bf16 during LDS staging (fuses the old
// k_f32_to_bf16 pass). OOB rows (beyond `rows`) staged as zero.
template <int HAS_SKIP, int A_F32>
__global__ __launch_bounds__(256) void k_gemm_ln(const void* __restrict__ Av,
                                                 const unsigned short* __restrict__ Bt,
                                                 const float* __restrict__ bias,
                                                 const float* __restrict__ gamma,
                                                 const float* __restrict__ beta,
                                                 const unsigned short* skip,
                                                 unsigned short* outb, int rows) {
  __shared__ unsigned short As[64][40];
  __shared__ unsigned short Bs[256][40];
  int tid = threadIdx.x;
  int wave = tid >> 6, lane = tid & 63;
  int quad = lane >> 4, l16 = lane & 15;
  size_t row0 = (size_t)blockIdx.x * 64;

  f32x4 acc[16];
#pragma unroll
  for (int i = 0; i < 16; i++) acc[i] = (f32x4){0.f, 0.f, 0.f, 0.f};

  int ar = tid >> 2, ac = (tid & 3) * 8;
  size_t arow = row0 + ar;
  for (int k0 = 0; k0 < 256; k0 += 32) {
    if (A_F32) {
      float4 f0 = make_float4(0.f, 0.f, 0.f, 0.f), f1 = f0;
      if (arow < (size_t)rows) {
        const float4* ap = (const float4*)((const float*)Av + arow * 256 + k0 + ac);
        f0 = ap[0];
        f1 = ap[1];
      }
      us4 u0 = {f2bf(f0.x), f2bf(f0.y), f2bf(f0.z), f2bf(f0.w)};
      us4 u1 = {f2bf(f1.x), f2bf(f1.y), f2bf(f1.z), f2bf(f1.w)};
      *(us4*)&As[ar][ac] = u0;
      *(us4*)&As[ar][ac + 4] = u1;
    } else {
      *(ushort8_t*)&As[ar][ac] =
          *(const ushort8_t*)&((const unsigned short*)Av)[arow * 256 + k0 + ac];
    }
    const unsigned short* bp = &Bt[(size_t)tid * 256 + k0];
    *(ushort8_t*)&Bs[tid][0] = *(const ushort8_t*)&bp[0];
    *(ushort8_t*)&Bs[tid][8] = *(const ushort8_t*)&bp[8];
    *(ushort8_t*)&Bs[tid][16] = *(const ushort8_t*)&bp[16];
    *(ushort8_t*)&Bs[tid][24] = *(const ushort8_t*)&bp[24];
    __syncthreads();
    short8_t afrag = *(const short8_t*)&As[wave * 16 + l16][quad * 8];
#pragma unroll
    for (int nt = 0; nt < 16; nt++) {
      short8_t bfrag = *(const short8_t*)&Bs[nt * 16 + l16][quad * 8];
      acc[nt] = __builtin_amdgcn_mfma_f32_16x16x32_bf16(afrag, bfrag, acc[nt], 0, 0, 0);
    }
    __syncthreads();
  }

  size_t rbase = row0 + wave * 16 + quad * 4;
#pragma unroll
  for (int nt = 0; nt < 16; nt++) {
    int col = nt * 16 + l16;
    float bv = bias[col];
#pragma unroll
    for (int r = 0; r < 4; r++) {
      float x = lrelu(acc[nt][r] + bv);
      if (HAS_SKIP) {
        if (rbase + r < (size_t)rows) x += bf2f(skip[(rbase + r) * 256 + col]);
      }
      acc[nt][r] = x;
    }
  }
  float s[4] = {0, 0, 0, 0}, q[4] = {0, 0, 0, 0};
#pragma unroll
  for (int nt = 0; nt < 16; nt++)
#pragma unroll
    for (int r = 0; r < 4; r++) {
      float x = acc[nt][r];
      s[r] += x;
      q[r] += x * x;
    }
#pragma unroll
  for (int o = 1; o < 16; o <<= 1)
#pragma unroll
    for (int r = 0; r < 4; r++) {
      s[r] += __shfl_xor(s[r], o);
      q[r] += __shfl_xor(q[r], o);
    }
  float mr[4], rs[4];
#pragma unroll
  for (int r = 0; r < 4; r++) {
    float m = s[r] * (1.f / 256.f);
    float v = q[r] * (1.f / 256.f) - m * m;
    mr[r] = m;
    rs[r] = rsqrtf(v + 1e-5f);
  }
#pragma unroll
  for (int nt = 0; nt < 16; nt++) {
    int col = nt * 16 + l16;
    float g = gamma[col], bb = beta[col];
#pragma unroll
    for (int r = 0; r < 4; r++) {
      if (rbase + r < (size_t)rows) {
        float y = (acc[nt][r] - mr[r]) * rs[r] * g + bb;
        outb[(rbase + r) * 256 + col] = f2bf(y);
      }
    }
  }
}

// ---------------- fused GEMM for HGNN: XW (bf16, in-place) + s1 = XW@a1 ----------
__global__ __launch_bounds__(256) void k_gemm_xw(unsigned short* A,
                                                 const unsigned short* __restrict__ Bt,
                                                 const float* __restrict__ a1,
                                                 float* __restrict__ s1, int rows) {
  __shared__ unsigned short As[64][40];
  __shared__ unsigned short Bs[256][40];
  int tid = threadIdx.x;
  int wave = tid >> 6, lane = tid & 63;
  int quad = lane >> 4, l16 = lane & 15;
  size_t row0 = (size_t)blockIdx.x * 64;

  f32x4 acc[16];
#pragma unroll
  for (int i = 0; i < 16; i++) acc[i] = (f32x4){0.f, 0.f, 0.f, 0.f};

  int ar = tid >> 2, ac = (tid & 3) * 8;
  for (int k0 = 0; k0 < 256; k0 += 32) {
    *(ushort8_t*)&As[ar][ac] = *(const ushort8_t*)&A[(row0 + ar) * 256 + k0 + ac];
    const unsigned short* bp = &Bt[(size_t)tid * 256 + k0];
    *(ushort8_t*)&Bs[tid][0] = *(const ushort8_t*)&bp[0];
    *(ushort8_t*)&Bs[tid][8] = *(const ushort8_t*)&bp[8];
    *(ushort8_t*)&Bs[tid][16] = *(const ushort8_t*)&bp[16];
    *(ushort8_t*)&Bs[tid][24] = *(const ushort8_t*)&bp[24];
    __syncthreads();
    short8_t afrag = *(const short8_t*)&As[wave * 16 + l16][quad * 8];
#pragma unroll
    for (int nt = 0; nt < 16; nt++) {
      short8_t bfrag = *(const short8_t*)&Bs[nt * 16 + l16][quad * 8];
      acc[nt] = __builtin_amdgcn_mfma_f32_16x16x32_bf16(afrag, bfrag, acc[nt], 0, 0, 0);
    }
    __syncthreads();
  }

  size_t rbase = row0 + wave * 16 + quad * 4;
  float s[4] = {0, 0, 0, 0};
#pragma unroll
  for (int nt = 0; nt < 16; nt++) {
    float av = a1[nt * 16 + l16];
#pragma unroll
    for (int r = 0; r < 4; r++) s[r] += acc[nt][r] * av;
  }
#pragma unroll
  for (int o = 1; o < 16; o <<= 1)
#pragma unroll
    for (int r = 0; r < 4; r++) s[r] += __shfl_xor(s[r], o);
#pragma unroll
  for (int nt = 0; nt < 16; nt++) {
    int col = nt * 16 + l16;
#pragma unroll
    for (int r = 0; r < 4; r++)
      if (rbase + r < (size_t)rows) A[(rbase + r) * 256 + col] = f2bf(acc[nt][r]);
  }
  if (l16 == 0) {
#pragma unroll
    for (int r = 0; r < 4; r++)
      if (rbase + r < (size_t)rows) s1[rbase + r] = s[r];
  }
}

// ---------------- CSR gathers ----------------
// Pass 1 loads CSR-ordered metadata lane-parallel (single hop). Accumulate pass
// broadcasts via __shfl and issues row loads in batches of 8 (MLP). EF is stored
// bf16 (halves the dominant random-row stream); s2 stays computed from the f32
// accumulator so attention weights are bit-identical to the f32-EF version.

// per hyperedge r (one wave): ef[r] = mean of XW[node] rows (bf16 out); s2[r] = ef_f32·a2
__global__ __launch_bounds__(256) void k_edge_gather(const unsigned short* __restrict__ XW,
                                                     const int* __restrict__ ES,
                                                     const int* __restrict__ NDe,
                                                     const float* __restrict__ a2,
                                                     unsigned short* __restrict__ EF,
                                                     float* __restrict__ s2, int nEdges) {
  int wave = threadIdx.x >> 6, lane = threadIdx.x & 63;
  int r = blockIdx.x * 4 + wave;
  if (r >= nEdges) return;
  int s = ES[r], e = ES[r + 1];
  int cnt = e - s;
  float4 acc = make_float4(0.f, 0.f, 0.f, 0.f);
  if (cnt <= 64) {
    int myn = 0;
    if (lane < cnt) myn = NDe[s + lane];
    for (int base = 0; base < cnt; base += 8) {
      us4 u[8];
      float f[8];
#pragma unroll
      for (int t = 0; t < 8; t++) {
        int j2 = base + t;  // <= 63 always (cnt <= 64)
        int n1 = __shfl(myn, j2);
        u[t] = ((const us4*)(XW + (size_t)n1 * 256))[lane];
        f[t] = (j2 < cnt) ? 1.f : 0.f;
      }
#pragma unroll
      for (int t = 0; t < 8; t++) {
        acc.x += f[t] * bf2f(u[t].x);
        acc.y += f[t] * bf2f(u[t].y);
        acc.z += f[t] * bf2f(u[t].z);
        acc.w += f[t] * bf2f(u[t].w);
      }
    }
  } else {
    for (int j = s; j < e; j++) {
      int n = NDe[j];
      us4 u = ((const us4*)(XW + (size_t)n * 256))[lane];
      acc.x += bf2f(u.x); acc.y += bf2f(u.y);
      acc.z += bf2f(u.z); acc.w += bf2f(u.w);
    }
  }
  float inv = 1.f / (float)(cnt > 1 ? cnt : 1);
  acc.x *= inv; acc.y *= inv; acc.z *= inv; acc.w *= inv;
  us4 ub = {f2bf(acc.x), f2bf(acc.y), f2bf(acc.z), f2bf(acc.w)};
  ((us4*)(EF + (size_t)r * 256))[lane] = ub;
  float4 a = ((const float4*)a2)[lane];
  float d = acc.x * a.x + acc.y * a.y + acc.z * a.z + acc.w * a.w;
  for (int o = 32; o; o >>= 1) d += __shfl_xor(d, o);
  if (lane == 0) s2[r] = d;
}

// per node n (one wave): in-wave softmax over incidences + weighted EF gather + lrelu
template <int WRITE_ATTN>
__global__ __launch_bounds__(256) void k_node_gather(const int* __restrict__ NS,
                                                     const int2* __restrict__ PE,
                                                     const float* __restrict__ s1,
                                                     const float* __restrict__ s2,
                                                     const unsigned short* __restrict__ EF,
                                                     unsigned short* outb, float* outf,
                                                     float* attn_out, int nNodes) {
  int wave = threadIdx.x >> 6, lane = threadIdx.x & 63;
  int n = blockIdx.x * 4 + wave;
  if (n >= nNodes) return;
  int s = NS[n], e = NS[n + 1];
  int cnt = e - s;
  float s1n = s1[n];
  float4 acc = make_float4(0.f, 0.f, 0.f, 0.f);
  if (cnt <= 64) {
    int mye0 = 0, myed = 0;
    float myscore = -3.4e38f;
    bool act = lane < cnt;
    if (act) {
      int2 pe = PE[s + lane];
      mye0 = pe.x;
      myed = pe.y;
      myscore = lrelu(s1n + s2[myed]);
    }
    float mymax = myscore;
    for (int o = 32; o; o >>= 1) mymax = fmaxf(mymax, __shfl_xor(mymax, o));
    float myexp = act ? __expf(myscore - mymax) : 0.f;
    float mysum = myexp;
    for (int o = 32; o; o >>= 1) mysum += __shfl_xor(mysum, o);
    float zinv = 1.f / fmaxf(mysum, 1e-9f);
    float myw = myexp * zinv;  // == 0 for inactive lanes
    if (WRITE_ATTN && act) attn_out[mye0] = myw;
    for (int base = 0; base < cnt; base += 8) {
      us4 v[8];
      float w[8];
#pragma unroll
      for (int t = 0; t < 8; t++) {
        int j2 = base + t;  // <= 63 always
        int ed = __shfl(myed, j2);
        w[t] = __shfl(myw, j2);
        v[t] = ((const us4*)(EF + (size_t)ed * 256))[lane];
      }
#pragma unroll
      for (int t = 0; t < 8; t++) {
        acc.x += w[t] * bf2f(v[t].x);
        acc.y += w[t] * bf2f(v[t].y);
        acc.z += w[t] * bf2f(v[t].z);
        acc.w += w[t] * bf2f(v[t].w);
      }
    }
  } else {
    float mymax = -3.4e38f;
    for (int j = s + lane; j < e; j += 64) {
      mymax = fmaxf(mymax, lrelu(s1n + s2[PE[j].y]));
    }
    for (int o = 32; o; o >>= 1) mymax = fmaxf(mymax, __shfl_xor(mymax, o));
    float mysum = 0.f;
    for (int j = s + lane; j < e; j += 64) {
      mysum += __expf(lrelu(s1n + s2[PE[j].y]) - mymax);
    }
    for (int o = 32; o; o >>= 1) mysum += __shfl_xor(mysum, o);
    float zinv = 1.f / fmaxf(mysum, 1e-9f);
    for (int j = s; j < e; j++) {
      int2 pe = PE[j];
      float w = __expf(lrelu(s1n + s2[pe.y]) - mymax) * zinv;
      if (WRITE_ATTN) {
        if (lane == 0) attn_out[pe.x] = w;
      }
      us4 v = ((const us4*)(EF + (size_t)pe.y * 256))[lane];
      acc.x += w * bf2f(v.x); acc.y += w * bf2f(v.y);
      acc.z += w * bf2f(v.z); acc.w += w * bf2f(v.w);
    }
  }
  acc.x = lrelu(acc.x); acc.y = lrelu(acc.y);
  acc.z = lrelu(acc.z); acc.w = lrelu(acc.w);
  if (outb) {
    us4 u = {f2bf(acc.x), f2bf(acc.y), f2bf(acc.z), f2bf(acc.w)};
    ((us4*)(outb + (size_t)n * 256))[lane] = u;
  } else {
    ((float4*)(outf + (size_t)n * 256))[lane] = acc;
  }
}

// per object o (one wave): msg[o] = sum of ev rows (bf16 in, bf16 out)
__global__ __launch_bounds__(256) void k_obj_gather(const unsigned short* __restrict__ EVB,
                                                    const int* __restrict__ OS,
                                                    const int* __restrict__ EVo,
                                                    unsigned short* __restrict__ outb,
                                                    int nObj) {
  int wave = threadIdx.x >> 6, lane = threadIdx.x & 63;
  int o = blockIdx.x * 4 + wave;
  if (o >= nObj) return;
  int s = OS[o], e = OS[o + 1];
  int cnt = e - s;
  float4 acc = make_float4(0.f, 0.f, 0.f, 0.f);
  if (cnt <= 64) {
    int myev = 0;
    if (lane < cnt) myev = EVo[s + lane];
    for (int base = 0; base < cnt; base += 8) {
      us4 u[8];
      float f[8];
#pragma unroll
      for (int t = 0; t < 8; t++) {
        int j2 = base + t;  // <= 63 always
        int v1 = __shfl(myev, j2);
        u[t] = ((const us4*)(EVB + (size_t)v1 * 256))[lane];
        f[t] = (j2 < cnt) ? 1.f : 0.f;
      }
#pragma unroll
      for (int t = 0; t < 8; t++) {
        acc.x += f[t] * bf2f(u[t].x);
        acc.y += f[t] * bf2f(u[t].y);
        acc.z += f[t] * bf2f(u[t].z);
        acc.w += f[t] * bf2f(u[t].w);
      }
    }
  } else {
    for (int j = s; j < e; j++) {
      int ev = EVo[j];
      us4 u = ((const us4*)(EVB + (size_t)ev * 256))[lane];
      acc.x += bf2f(u.x); acc.y += bf2f(u.y);
      acc.z += bf2f(u.z); acc.w += bf2f(u.w);
    }
  }
  us4 u = {f2bf(acc.x), f2bf(acc.y), f2bf(acc.z), f2bf(acc.w)};
  ((us4*)(outb + (size_t)o * 256))[lane] = u;
}

// ---------------- driver ----------------

extern "C" void kernel_launch(void* const* d_in, const int* in_sizes, int n_in,
                              void* d_out, int out_size, void* d_ws, size_t ws_size,
                              hipStream_t stream) {
  (void)n_in; (void)out_size;
  const float* object_X = (const float*)d_in[0];
  const float* event_X = (const float*)d_in[1];
  const float* Wo = (const float*)d_in[2];   const float* bo = (const float*)d_in[3];
  const float* go = (const float*)d_in[4];   const float* bon = (const float*)d_in[5];
  const float* We = (const float*)d_in[6];   const float* be = (const float*)d_in[7];
  const float* ge = (const float*)d_in[8];   const float* ben = (const float*)d_in[9];
  const float* Wu = (const float*)d_in[10];  const float* bu = (const float*)d_in[11];
  const float* Wl = (const float*)d_in[12];  const float* bl = (const float*)d_in[13];
  const float* g1 = (const float*)d_in[14];  const float* b1 = (const float*)d_in[15];
  const float* g2 = (const float*)d_in[16];  const float* b2 = (const float*)d_in[17];
  const float* Wh1 = (const float*)d_in[18]; const float* ah1 = (const float*)d_in[19];
  const float* Wh2 = (const float*)d_in[20]; const float* ah2 = (const float*)d_in[21];
  const int* oe_ev = (const int*)d_in[22];
  const int* oe_obj = (const int*)d_in[23];
  const int* hg_node = (const int*)d_in[24];
  const int* hg_edge = (const int*)d_in[25];

  const int N_OBJ = in_sizes[0] / 256;
  const int N_EV = in_sizes[1] / 256;
  const int E1 = in_sizes[22];
  const int E2 = in_sizes[24];
  const int NN = N_EV + N_OBJ;
  const int MEV = ((N_EV + 63) / 64) * 64;
  const int MOB = ((N_OBJ + 63) / 64) * 64;
  const int MX = ((NN + 63) / 64) * 64;
  const int EMX = E2 > E1 ? E2 : E1;

  char* p = (char*)d_ws;
  auto take = [&](size_t bytes) {
    char* r = p;
    p += (bytes + 255) & ~(size_t)255;
    return r;
  };
  unsigned short* WT = (unsigned short*)take((size_t)6 * 65536 * 2);  // 0.79 MB
  unsigned short* XBF = (unsigned short*)take((size_t)MX * 256 * 2);  // 76.8 MB  X / XW / h
  unsigned short* SB = (unsigned short*)take((size_t)MOB * 256 * 2);  // 51.2 MB staging
  unsigned short* EF = SB;  // alias (bf16): SB dead once the obj2 GEMM has consumed it
  float* S1 = (float*)take((size_t)NN * 4);
  float* S2 = (float*)take((size_t)N_EV * 4);
  int* NS = (int*)take((size_t)(NN + 1) * 4);      // node CSR starts
  int* ES = (int*)take((size_t)(N_EV + 1) * 4);    // edge CSR starts
  int* OS = (int*)take((size_t)(N_OBJ + 1) * 4);   // obj CSR starts
  int* CNTn = (int*)take((size_t)NN * 4);          // counts, reused as fill cursors
  int* CNTe = (int*)take((size_t)N_EV * 4);
  int* CNTo = (int*)take((size_t)N_OBJ * 4);
  int2* PEn = (int2*)take((size_t)E2 * 8);         // (e0, hg_edge[e0]) in node-CSR order
  int* NDe = (int*)take((size_t)E2 * 4);           // hg_node values in edge-CSR order
  int* EVo = (int*)take((size_t)E1 * 4);           // oe_ev values in obj-CSR order
  size_t need = (size_t)(p - (char*)d_ws);
  if (need > ws_size)
    fprintf(stderr, "[kernel_launch] WS OVERFLOW: need=%zu have=%zu\n", need, ws_size);

  float* out = (float*)d_out;
  // obj skip (bf16, 51.2 MB) lives in d_out — dead region until layer-2 outputs
  unsigned short* OBJB = (unsigned short*)d_out;

  // --- weights -> bf16 transposed (one fused launch; slots: We,Wo,Wu,Wl,Wh1,Wh2) ---
  k_transpose_w6<<<6 * 256, 256, 0, stream>>>(We, Wo, Wu, Wl, Wh1, Wh2, WT);

  if (MX > NN)
    hipMemsetAsync(XBF + (size_t)NN * 256, 0, (size_t)(MX - NN) * 512, stream);

  // --- CSR builds (node/E2, edge/E2, obj/E1), fused ---
  size_t cnt_span = (size_t)((char*)PEn - (char*)CNTn);  // CNTn..CNTo contiguous
  hipMemsetAsync(CNTn, 0, cnt_span, stream);
  k_count3<<<(EMX + 255) / 256, 256, 0, stream>>>(hg_node, hg_edge, oe_obj, CNTn, CNTe, CNTo,
                                                  E2, E1);
  k_scan3<<<3, 1024, 0, stream>>>(CNTn, NS, NN, CNTe, ES, N_EV, CNTo, OS, N_OBJ);
  hipMemsetAsync(CNTn, 0, cnt_span, stream);
  k_fill3<<<(EMX + 255) / 256, 256, 0, stream>>>(hg_node, hg_edge, oe_ev, oe_obj, NS, ES, OS,
                                                 CNTn, CNTe, CNTo, PEn, NDe, EVo, E2, E1);

  // --- ev = LN(lrelu(event_X@We + be)) -> XBF rows [0,N_EV) bf16 (f32 A fused) ---
  k_gemm_ln<0, 1><<<MEV / 64, 256, 0, stream>>>(event_X, WT + 0 * 65536, be, ge, ben, nullptr,
                                                XBF, N_EV);
  // --- obj = LN(lrelu(object_X@Wo + bo)) -> OBJB bf16 (in d_out) ---
  k_gemm_ln<0, 1><<<MOB / 64, 256, 0, stream>>>(object_X, WT + 1 * 65536, bo, go, bon, nullptr,
                                                OBJB, N_OBJ);
  // --- msg (CSR gather, bf16) -> SB; obj1 = LN(lrelu(msg@Wu+bu)+obj) -> SB ---
  k_obj_gather<<<(N_OBJ + 3) / 4, 256, 0, stream>>>(XBF, OS, EVo, SB, N_OBJ);
  k_gemm_ln<1, 0><<<MOB / 64, 256, 0, stream>>>(SB, WT + 2 * 65536, bu, g1, b1, OBJB, SB,
                                                N_OBJ);
  // --- obj2 = LN(lrelu(obj1@Wl+bl)+obj1) -> XBF rows [N_EV,NN) bf16 ---
  k_gemm_ln<1, 0><<<MOB / 64, 256, 0, stream>>>(SB, WT + 3 * 65536, bl, g2, b2, SB,
                                                XBF + (size_t)N_EV * 256, N_OBJ);

  // --- HGNN layer 1: h -> XBF bf16 (SB now dead; EF aliases it) ---
  k_gemm_xw<<<MX / 64, 256, 0, stream>>>(XBF, WT + 4 * 65536, ah1, S1, NN);
  k_edge_gather<<<(N_EV + 3) / 4, 256, 0, stream>>>(XBF, ES, NDe, ah1 + 256, EF, S2, N_EV);
  k_node_gather<0><<<(NN + 3) / 4, 256, 0, stream>>>(NS, PEn, S1, S2, EF, XBF, nullptr,
                                                     nullptr, NN);
  // --- HGNN layer 2: h f32 + attn -> d_out ---
  k_gemm_xw<<<MX / 64, 256, 0, stream>>>(XBF, WT + 5 * 65536, ah2, S1, NN);
  k_edge_gather<<<(N_EV + 3) / 4, 256, 0, stream>>>(XBF, ES, NDe, ah2 + 256, EF, S2, N_EV);
  k_node_gather<1><<<(NN + 3) / 4, 256, 0, stream>>>(NS, PEn, S1, S2, EF, nullptr, out,
                                                     out + (size_t)NN * 256, NN);
}